// Round 1
// baseline (4202.522 us; speedup 1.0000x reference)
//
#include <hip/hip_runtime.h>
#include <math.h>

#define LL   2048
#define DDIM 512
#define CD   21
#define CLIPD 10
#define TI   8      // rows (i) per block
#define NJC  8      // j-chunks of 256 -> 2048 cols
#define NTHREADS 256

__global__ __launch_bounds__(NTHREADS) void rpa_fused_kernel(
    const float* __restrict__ key,     // [B, L, D]
    const int*   __restrict__ mask,    // [B, L]  (1 = masked)
    const float* __restrict__ params,  // [C, D]
    float*       __restrict__ out)     // [B, L, L]
{
    __shared__ float As[TI][DDIM];        // 16 KB, i-major
    __shared__ float kp[TI][CD];          // bias per (row, dist)
    __shared__ float red[2][TI][4];       // per-wave partials (max, sum)

    const int t  = threadIdx.x;
    const int b  = blockIdx.y;
    const int i0 = blockIdx.x * TI;

    const float* keyb = key + (size_t)b * LL * DDIM;

    // ---- stage A rows into LDS (coalesced float4) ----
    {
        const float4* src = (const float4*)(keyb + (size_t)i0 * DDIM);
        float4* dst = (float4*)&As[0][0];
        #pragma unroll
        for (int k = 0; k < (TI * DDIM / 4) / NTHREADS; ++k)   // 4 iters
            dst[k * NTHREADS + t] = src[k * NTHREADS + t];
    }
    __syncthreads();

    // ---- kp[i][c] = dot(A[i], params[c])  (168 dots, threads 0..167) ----
    if (t < TI * CD) {
        const int i = t / CD, c = t % CD;
        const float4* p4 = (const float4*)(params + c * DDIM);
        const float4* a4 = (const float4*)&As[i][0];
        float s = 0.f;
        #pragma unroll 4
        for (int d4 = 0; d4 < DDIM / 4; ++d4) {
            float4 a = a4[d4], p = p4[d4];
            s += a.x * p.x + a.y * p.y + a.z * p.z + a.w * p.w;
        }
        kp[i][c] = s;
    }
    // (kp consumed only after the post-main-loop __syncthreads)

    // ---- main loop: acc[i][jc] = dot(A[i], K[jc*256+t]) ----
    float acc[TI][NJC];
    #pragma unroll
    for (int i = 0; i < TI; ++i)
        #pragma unroll
        for (int jc = 0; jc < NJC; ++jc) acc[i][jc] = 0.f;

    const float4* kb4 = (const float4*)keyb;   // [L][128] float4
    #pragma unroll 1
    for (int d4 = 0; d4 < DDIM / 4; ++d4) {
        float4 a[TI];
        #pragma unroll
        for (int i = 0; i < TI; ++i)
            a[i] = *(const float4*)&As[i][d4 * 4];   // broadcast b128

        float4 bb[NJC];
        #pragma unroll
        for (int jc = 0; jc < NJC; ++jc)
            bb[jc] = kb4[(size_t)(jc * NTHREADS + t) * (DDIM / 4) + d4];

        #pragma unroll
        for (int jc = 0; jc < NJC; ++jc) {
            #pragma unroll
            for (int i = 0; i < TI; ++i) {
                acc[i][jc] += a[i].x * bb[jc].x;
                acc[i][jc] += a[i].y * bb[jc].y;
                acc[i][jc] += a[i].z * bb[jc].z;
                acc[i][jc] += a[i].w * bb[jc].w;
            }
        }
    }
    __syncthreads();   // kp ready; As no longer needed

    // ---- mask values for this thread's 8 columns ----
    int mk[NJC];
    #pragma unroll
    for (int jc = 0; jc < NJC; ++jc)
        mk[jc] = mask[b * LL + jc * NTHREADS + t];

    const int wave = t >> 6;

    // ---- E1: bias + mask + per-row max ----
    #pragma unroll
    for (int i = 0; i < TI; ++i) {
        const int gi = i0 + i;
        float mx = -INFINITY;
        #pragma unroll
        for (int jc = 0; jc < NJC; ++jc) {
            const int j = jc * NTHREADS + t;
            int rel = j - gi;
            rel = (rel < -CLIPD) ? -CLIPD : (rel > CLIPD ? CLIPD : rel);
            float v = acc[i][jc] + kp[i][rel + CLIPD];
            v = mk[jc] ? -1e20f : v;
            acc[i][jc] = v;
            mx = fmaxf(mx, v);
        }
        #pragma unroll
        for (int off = 32; off; off >>= 1)
            mx = fmaxf(mx, __shfl_xor(mx, off));
        if ((t & 63) == 0) red[0][i][wave] = mx;
    }
    __syncthreads();

    // ---- E2: exp + per-row sum ----
    #pragma unroll
    for (int i = 0; i < TI; ++i) {
        const float mx = fmaxf(fmaxf(red[0][i][0], red[0][i][1]),
                               fmaxf(red[0][i][2], red[0][i][3]));
        float s = 0.f;
        #pragma unroll
        for (int jc = 0; jc < NJC; ++jc) {
            float e = __expf(acc[i][jc] - mx);
            acc[i][jc] = e;
            s += e;
        }
        #pragma unroll
        for (int off = 32; off; off >>= 1)
            s += __shfl_xor(s, off);
        if ((t & 63) == 0) red[1][i][wave] = s;
    }
    __syncthreads();

    // ---- E3: normalize + store (coalesced dwords) ----
    #pragma unroll
    for (int i = 0; i < TI; ++i) {
        const int gi = i0 + i;
        const float l = red[1][i][0] + red[1][i][1] + red[1][i][2] + red[1][i][3];
        const float inv = 1.0f / l;
        float* orow = out + ((size_t)b * LL + gi) * LL;
        #pragma unroll
        for (int jc = 0; jc < NJC; ++jc)
            orow[jc * NTHREADS + t] = acc[i][jc] * inv;
    }
}

extern "C" void kernel_launch(void* const* d_in, const int* in_sizes, int n_in,
                              void* d_out, int out_size, void* d_ws, size_t ws_size,
                              hipStream_t stream) {
    const float* key    = (const float*)d_in[0];
    const int*   mask   = (const int*)d_in[1];
    const float* params = (const float*)d_in[2];
    float*       out    = (float*)d_out;

    const int B = in_sizes[0] / (LL * DDIM);   // 16

    dim3 grid(LL / TI, B);
    dim3 block(NTHREADS);
    rpa_fused_kernel<<<grid, block, 0, stream>>>(key, mask, params, out);
}

// Round 2
// 1271.558 us; speedup vs baseline: 3.3050x; 3.3050x over previous
//
#include <hip/hip_runtime.h>
#include <math.h>

#define LL    2048
#define DD    512
#define CD    21
#define CLIPD 10
#define BT    128      // output tile (BT x BT)
#define BK    16       // k-chunk
#define NT    256      // threads per GEMM block
#define LDSROW 136     // padded LDS row stride (floats); 544 B, 16B-aligned

// ---------- kernel 1: kp[b][i][c] = dot(key[b][i], params[c]) ----------
__global__ __launch_bounds__(256) void kp_kernel(
    const float* __restrict__ key,     // [B*L, D]
    const float* __restrict__ params,  // [C, D]
    float*       __restrict__ kp)      // [B*L, C]
{
    const int ri = blockIdx.x * 256 + threadIdx.x;       // 0..32767
    const float4* k4 = (const float4*)key + (size_t)ri * (DD / 4);
    const float4* p4 = (const float4*)params;

    float acc[CD];
    #pragma unroll
    for (int c = 0; c < CD; ++c) acc[c] = 0.f;

    for (int d = 0; d < DD / 4; ++d) {
        const float4 kv = k4[d];
        #pragma unroll
        for (int c = 0; c < CD; ++c) {
            const float4 pv = p4[c * (DD / 4) + d];      // uniform -> scalar load
            acc[c] += kv.x * pv.x + kv.y * pv.y + kv.z * pv.z + kv.w * pv.w;
        }
    }
    #pragma unroll
    for (int c = 0; c < CD; ++c) kp[(size_t)ri * CD + c] = acc[c];
}

// ---------- kernel 2: scores = K K^T + bias, mask; write to out ----------
__global__ __launch_bounds__(NT) void gemm_bias_mask_kernel(
    const float* __restrict__ key,   // [B, L, D]
    const int*   __restrict__ mask,  // [B, L]
    const float* __restrict__ kp,    // [B, L, C]
    float*       __restrict__ out)   // [B, L, L] (scores)
{
    __shared__ float As[BK][LDSROW];          // k-major A tile
    __shared__ float Bs[BK][LDSROW];          // k-major B tile
    __shared__ float kps[BT][CD + 1];         // bias rows for this i-tile

    const int t  = threadIdx.x;
    const int bz = blockIdx.z;
    const int i0 = blockIdx.y * BT;
    const int j0 = blockIdx.x * BT;

    const float*  keyb  = key + (size_t)bz * LL * DD;
    const float4* keyb4 = (const float4*)keyb;

    // stage kp slice for this row tile (visibility via main-loop barriers)
    for (int idx = t; idx < BT * CD; idx += NT) {
        const int i = idx / CD, c = idx % CD;
        kps[i][c] = kp[((size_t)bz * LL + i0 + i) * CD + c];
    }

    const int tx = t & 15;          // 0..15 (cols)
    const int ty = t >> 4;          // 0..15 (rows)

    float acc[2][2][4][4] = {};

    for (int kt = 0; kt < DD / BK; ++kt) {
        // ---- stage A and B tiles, transposing to k-major ----
        #pragma unroll
        for (int r = 0; r < 2; ++r) {
            const int flat = t + NT * r;
            const int i  = flat >> 2;       // 0..127
            const int k4 = flat & 3;        // 0..3
            const float4 av = keyb4[(size_t)(i0 + i) * (DD / 4) + kt * 4 + k4];
            const float4 bv = keyb4[(size_t)(j0 + i) * (DD / 4) + kt * 4 + k4];
            As[4 * k4 + 0][i] = av.x; As[4 * k4 + 1][i] = av.y;
            As[4 * k4 + 2][i] = av.z; As[4 * k4 + 3][i] = av.w;
            Bs[4 * k4 + 0][i] = bv.x; Bs[4 * k4 + 1][i] = bv.y;
            Bs[4 * k4 + 2][i] = bv.z; Bs[4 * k4 + 3][i] = bv.w;
        }
        __syncthreads();

        // ---- 8x8 micro-tile FMA ----
        #pragma unroll
        for (int k = 0; k < BK; ++k) {
            const float4 a0 = *(const float4*)&As[k][4 * ty];
            const float4 a1 = *(const float4*)&As[k][4 * ty + 64];
            const float4 b0 = *(const float4*)&Bs[k][4 * tx];
            const float4 b1 = *(const float4*)&Bs[k][4 * tx + 64];
            const float ar[2][4] = {{a0.x, a0.y, a0.z, a0.w}, {a1.x, a1.y, a1.z, a1.w}};
            const float br[2][4] = {{b0.x, b0.y, b0.z, b0.w}, {b1.x, b1.y, b1.z, b1.w}};
            #pragma unroll
            for (int p = 0; p < 2; ++p)
                #pragma unroll
                for (int q = 0; q < 2; ++q)
                    #pragma unroll
                    for (int rr = 0; rr < 4; ++rr)
                        #pragma unroll
                        for (int cc = 0; cc < 4; ++cc)
                            acc[p][q][rr][cc] += ar[p][rr] * br[q][cc];
        }
        __syncthreads();
    }

    // ---- epilogue: bias + mask, store scores ----
    const int* maskb = mask + (size_t)bz * LL;
    int4 mk[2];
    mk[0] = ((const int4*)maskb)[(j0 >> 2) + tx];
    mk[1] = ((const int4*)maskb)[(j0 >> 2) + tx + 16];

    #pragma unroll
    for (int p = 0; p < 2; ++p)
        #pragma unroll
        for (int rr = 0; rr < 4; ++rr) {
            const int li  = 4 * ty + 64 * p + rr;
            const int row = i0 + li;
            #pragma unroll
            for (int q = 0; q < 2; ++q) {
                const int colbase = j0 + 4 * tx + 64 * q;
                float4 v;
                float* vv = (float*)&v;
                const int* mm = (const int*)&mk[q];
                #pragma unroll
                for (int cc = 0; cc < 4; ++cc) {
                    const int col = colbase + cc;
                    int rel = col - row;
                    rel = rel < -CLIPD ? -CLIPD : (rel > CLIPD ? CLIPD : rel);
                    const float x = acc[p][q][rr][cc] + kps[li][rel + CLIPD];
                    vv[cc] = mm[cc] ? -1e20f : x;
                }
                *(float4*)&out[((size_t)bz * LL + row) * LL + colbase] = v;
            }
        }
}

// ---------- kernel 3: in-place row softmax ----------
__global__ __launch_bounds__(256) void softmax_kernel(float* __restrict__ out) {
    const int row  = blockIdx.x * 4 + (threadIdx.x >> 6);
    const int lane = threadIdx.x & 63;
    float4* r4 = (float4*)out + (size_t)row * (LL / 4);

    float4 v[8];
    float mx = -INFINITY;
    #pragma unroll
    for (int c = 0; c < 8; ++c) {
        v[c] = r4[lane + 64 * c];
        mx = fmaxf(mx, fmaxf(fmaxf(v[c].x, v[c].y), fmaxf(v[c].z, v[c].w)));
    }
    #pragma unroll
    for (int off = 32; off; off >>= 1) mx = fmaxf(mx, __shfl_xor(mx, off));

    float s = 0.f;
    #pragma unroll
    for (int c = 0; c < 8; ++c) {
        v[c].x = __expf(v[c].x - mx); v[c].y = __expf(v[c].y - mx);
        v[c].z = __expf(v[c].z - mx); v[c].w = __expf(v[c].w - mx);
        s += v[c].x + v[c].y + v[c].z + v[c].w;
    }
    #pragma unroll
    for (int off = 32; off; off >>= 1) s += __shfl_xor(s, off);

    const float inv = 1.0f / s;
    #pragma unroll
    for (int c = 0; c < 8; ++c) {
        v[c].x *= inv; v[c].y *= inv; v[c].z *= inv; v[c].w *= inv;
        r4[lane + 64 * c] = v[c];
    }
}

extern "C" void kernel_launch(void* const* d_in, const int* in_sizes, int n_in,
                              void* d_out, int out_size, void* d_ws, size_t ws_size,
                              hipStream_t stream) {
    const float* key    = (const float*)d_in[0];
    const int*   mask   = (const int*)d_in[1];
    const float* params = (const float*)d_in[2];
    float*       out    = (float*)d_out;
    float*       kp     = (float*)d_ws;           // 16*2048*21*4 = 2.75 MB

    const int B = in_sizes[0] / (LL * DD);        // 16
    const int nrows = B * LL;                     // 32768

    kp_kernel<<<dim3(nrows / 256), dim3(256), 0, stream>>>(key, params, kp);

    dim3 ggrid(LL / BT, LL / BT, B);              // 16 x 16 x 16
    gemm_bias_mask_kernel<<<ggrid, dim3(NT), 0, stream>>>(key, mask, kp, out);

    softmax_kernel<<<dim3(nrows / 4), dim3(256), 0, stream>>>(out);
}

// Round 3
// 699.496 us; speedup vs baseline: 6.0079x; 1.8178x over previous
//
#include <hip/hip_runtime.h>
#include <math.h>

#define LL    2048
#define DD    512
#define CD    21
#define CLIPD 10
#define NT    256
#define KPAD  40       // LDS row stride in bf16 units (80 B) -> max 2-way bank alias (free)

typedef __attribute__((ext_vector_type(8))) short bf16x8;
typedef __attribute__((ext_vector_type(4))) float f32x4;

__device__ __forceinline__ unsigned short bf16_rn(float x) {
    union { float f; unsigned u; } v; v.f = x;
    return (unsigned short)((v.u + 0x7FFFu + ((v.u >> 16) & 1u)) >> 16);
}
__device__ __forceinline__ float bf16_f(unsigned short h) {
    union { float f; unsigned u; } v; v.u = ((unsigned)h) << 16;
    return v.f;
}

// ---------- kernel 1: kp[b][i][c] = dot(key[b][i], params[c]) ----------
__global__ __launch_bounds__(256) void kp_kernel(
    const float* __restrict__ key,     // [B*L, D]
    const float* __restrict__ params,  // [C, D]
    float*       __restrict__ kp)      // [B*L, C]
{
    __shared__ float4 pL[CD * (DD / 4)];          // 21*128 float4 = 43 KB
    const int t = threadIdx.x;
    for (int idx = t; idx < CD * (DD / 4); idx += 256)
        pL[idx] = ((const float4*)params)[idx];
    __syncthreads();

    const int ri = blockIdx.x * 256 + t;
    const float4* k4 = (const float4*)key + (size_t)ri * (DD / 4);

    float acc[CD];
    #pragma unroll
    for (int c = 0; c < CD; ++c) acc[c] = 0.f;

    for (int d = 0; d < DD / 4; ++d) {
        const float4 kv = k4[d];
        #pragma unroll
        for (int c = 0; c < CD; ++c) {
            const float4 pv = pL[c * (DD / 4) + d];   // LDS broadcast
            acc[c] += kv.x * pv.x + kv.y * pv.y + kv.z * pv.z + kv.w * pv.w;
        }
    }
    #pragma unroll
    for (int c = 0; c < CD; ++c) kp[(size_t)ri * CD + c] = acc[c];
}

// ---------- kernel 2: scores = K K^T + bias, mask (bf16 hi/lo split MFMA) ----------
__global__ __launch_bounds__(NT) void gemm_mfma_kernel(
    const float* __restrict__ key,   // [B, L, D]
    const int*   __restrict__ mask,  // [B, L]
    const float* __restrict__ kp,    // [B, L, C]
    float*       __restrict__ out)   // [B, L, L]
{
    __shared__ unsigned short Ah[128 * KPAD];   // 10 KB each
    __shared__ unsigned short Al[128 * KPAD];
    __shared__ unsigned short Bhs[128 * KPAD];
    __shared__ unsigned short Bls[128 * KPAD];
    __shared__ float kps[128 * (CD + 1)];       // 11 KB

    const int t  = threadIdx.x;
    const int bz = blockIdx.z;
    const int i0 = blockIdx.y * 128;
    const int j0 = blockIdx.x * 128;

    const float4* keyb4 = (const float4*)(key + (size_t)bz * LL * DD);

    // stage bias rows (visible after first k-loop barrier; read only in epilogue)
    for (int idx = t; idx < 128 * CD; idx += NT) {
        const int i = idx / CD, c = idx % CD;
        kps[i * (CD + 1) + c] = kp[((size_t)bz * LL + i0 + i) * CD + c];
    }

    const int lane = t & 63, wave = t >> 6;
    const int wr = wave >> 1, wc = wave & 1;     // 2x2 wave grid, 64x64 each
    const int quad = lane >> 4, l16 = lane & 15;

    f32x4 acc[4][4];
    #pragma unroll
    for (int mt = 0; mt < 4; ++mt)
        #pragma unroll
        for (int nt = 0; nt < 4; ++nt)
            acc[mt][nt] = (f32x4){0.f, 0.f, 0.f, 0.f};

    for (int kt = 0; kt < DD / 32; ++kt) {
        // ---- stage: fp32 -> bf16 hi/lo, k-contiguous rows ----
        #pragma unroll
        for (int r = 0; r < 2; ++r) {
            const int flat = t + NT * r;          // 0..511
            const int row  = flat >> 2;           // 0..127
            const int kq2  = flat & 3;            // float4-pair index
            #pragma unroll
            for (int h = 0; h < 2; ++h) {
                const int kq = kq2 * 2 + h;       // 0..7
                const float4 av = keyb4[(size_t)(i0 + row) * (DD / 4) + kt * 8 + kq];
                const float4 bv = keyb4[(size_t)(j0 + row) * (DD / 4) + kt * 8 + kq];
                ushort4 ah4, al4, bh4, bl4;
                ah4.x = bf16_rn(av.x); al4.x = bf16_rn(av.x - bf16_f(ah4.x));
                ah4.y = bf16_rn(av.y); al4.y = bf16_rn(av.y - bf16_f(ah4.y));
                ah4.z = bf16_rn(av.z); al4.z = bf16_rn(av.z - bf16_f(ah4.z));
                ah4.w = bf16_rn(av.w); al4.w = bf16_rn(av.w - bf16_f(ah4.w));
                bh4.x = bf16_rn(bv.x); bl4.x = bf16_rn(bv.x - bf16_f(bh4.x));
                bh4.y = bf16_rn(bv.y); bl4.y = bf16_rn(bv.y - bf16_f(bh4.y));
                bh4.z = bf16_rn(bv.z); bl4.z = bf16_rn(bv.z - bf16_f(bh4.z));
                bh4.w = bf16_rn(bv.w); bl4.w = bf16_rn(bv.w - bf16_f(bh4.w));
                *(ushort4*)&Ah [row * KPAD + kq * 4] = ah4;
                *(ushort4*)&Al [row * KPAD + kq * 4] = al4;
                *(ushort4*)&Bhs[row * KPAD + kq * 4] = bh4;
                *(ushort4*)&Bls[row * KPAD + kq * 4] = bl4;
            }
        }
        __syncthreads();

        // ---- fragments (ds_read_b128, k-contiguous) ----
        bf16x8 fah[4], fal[4], fbh[4], fbl[4];
        #pragma unroll
        for (int x = 0; x < 4; ++x) {
            const int m = wr * 64 + x * 16 + l16;
            const int n = wc * 64 + x * 16 + l16;
            fah[x] = *(const bf16x8*)&Ah [m * KPAD + quad * 8];
            fal[x] = *(const bf16x8*)&Al [m * KPAD + quad * 8];
            fbh[x] = *(const bf16x8*)&Bhs[n * KPAD + quad * 8];
            fbl[x] = *(const bf16x8*)&Bls[n * KPAD + quad * 8];
        }

        // ---- 48 MFMAs: hi*hi + hi*lo + lo*hi ----
        #pragma unroll
        for (int mt = 0; mt < 4; ++mt)
            #pragma unroll
            for (int nt = 0; nt < 4; ++nt) {
                acc[mt][nt] = __builtin_amdgcn_mfma_f32_16x16x32_bf16(fah[mt], fbh[nt], acc[mt][nt], 0, 0, 0);
                acc[mt][nt] = __builtin_amdgcn_mfma_f32_16x16x32_bf16(fah[mt], fbl[nt], acc[mt][nt], 0, 0, 0);
                acc[mt][nt] = __builtin_amdgcn_mfma_f32_16x16x32_bf16(fal[mt], fbh[nt], acc[mt][nt], 0, 0, 0);
            }
        __syncthreads();
    }

    // ---- epilogue: bias + mask + store ----
    const int* maskb = mask + (size_t)bz * LL;
    int mkv[4];
    #pragma unroll
    for (int nt = 0; nt < 4; ++nt)
        mkv[nt] = maskb[j0 + wc * 64 + nt * 16 + l16];

    #pragma unroll
    for (int mt = 0; mt < 4; ++mt)
        #pragma unroll
        for (int r = 0; r < 4; ++r) {
            const int li   = wr * 64 + mt * 16 + quad * 4 + r;
            const int grow = i0 + li;
            float* orow = out + ((size_t)bz * LL + grow) * LL;
            #pragma unroll
            for (int nt = 0; nt < 4; ++nt) {
                const int col = j0 + wc * 64 + nt * 16 + l16;
                int rel = col - grow;
                rel = rel < -CLIPD ? -CLIPD : (rel > CLIPD ? CLIPD : rel);
                const float v = acc[mt][nt][r] + kps[li * (CD + 1) + rel + CLIPD];
                orow[col] = mkv[nt] ? -1e20f : v;
            }
        }
}

// ---------- kernel 3: in-place row softmax ----------
__global__ __launch_bounds__(256) void softmax_kernel(float* __restrict__ out) {
    const int row  = blockIdx.x * 4 + (threadIdx.x >> 6);
    const int lane = threadIdx.x & 63;
    float4* r4 = (float4*)out + (size_t)row * (LL / 4);

    float4 v[8];
    float mx = -INFINITY;
    #pragma unroll
    for (int c = 0; c < 8; ++c) {
        v[c] = r4[lane + 64 * c];
        mx = fmaxf(mx, fmaxf(fmaxf(v[c].x, v[c].y), fmaxf(v[c].z, v[c].w)));
    }
    #pragma unroll
    for (int off = 32; off; off >>= 1) mx = fmaxf(mx, __shfl_xor(mx, off));

    float s = 0.f;
    #pragma unroll
    for (int c = 0; c < 8; ++c) {
        v[c].x = __expf(v[c].x - mx); v[c].y = __expf(v[c].y - mx);
        v[c].z = __expf(v[c].z - mx); v[c].w = __expf(v[c].w - mx);
        s += v[c].x + v[c].y + v[c].z + v[c].w;
    }
    #pragma unroll
    for (int off = 32; off; off >>= 1) s += __shfl_xor(s, off);

    const float inv = 1.0f / s;
    #pragma unroll
    for (int c = 0; c < 8; ++c) {
        v[c].x *= inv; v[c].y *= inv; v[c].z *= inv; v[c].w *= inv;
        r4[lane + 64 * c] = v[c];
    }
}

extern "C" void kernel_launch(void* const* d_in, const int* in_sizes, int n_in,
                              void* d_out, int out_size, void* d_ws, size_t ws_size,
                              hipStream_t stream) {
    const float* key    = (const float*)d_in[0];
    const int*   mask   = (const int*)d_in[1];
    const float* params = (const float*)d_in[2];
    float*       out    = (float*)d_out;
    float*       kp     = (float*)d_ws;           // 16*2048*21*4 = 2.75 MB

    const int B = in_sizes[0] / (LL * DD);        // 16
    const int nrows = B * LL;                     // 32768

    kp_kernel<<<dim3(nrows / 256), dim3(256), 0, stream>>>(key, params, kp);

    dim3 ggrid(LL / 128, LL / 128, B);            // 16 x 16 x 16
    gemm_mfma_kernel<<<ggrid, dim3(NT), 0, stream>>>(key, mask, kp, out);

    softmax_kernel<<<dim3(nrows / 4), dim3(256), 0, stream>>>(out);
}

// Round 4
// 670.737 us; speedup vs baseline: 6.2655x; 1.0429x over previous
//
#include <hip/hip_runtime.h>
#include <math.h>

#define LL    2048
#define DD    512
#define CD    21
#define CLIPD 10
#define NT    256
#define KPAD  40       // fallback-path LDS row stride (bf16) -> 2-way alias (free)

typedef __attribute__((ext_vector_type(8))) short bf16x8;
typedef __attribute__((ext_vector_type(4))) float f32x4;

typedef __attribute__((address_space(3))) unsigned int        as3_u32;
typedef const __attribute__((address_space(1))) unsigned int  as1_u32;

__device__ __forceinline__ void dma16(const void* g, void* l) {
    __builtin_amdgcn_global_load_lds((as1_u32*)g, (as3_u32*)l, 16, 0, 0);
}

__device__ __forceinline__ unsigned short bf16_rn(float x) {
    union { float f; unsigned u; } v; v.f = x;
    return (unsigned short)((v.u + 0x7FFFu + ((v.u >> 16) & 1u)) >> 16);
}
__device__ __forceinline__ float bf16_f(unsigned short h) {
    union { float f; unsigned u; } v; v.u = ((unsigned)h) << 16;
    return v.f;
}

// ---------- kernel 0: fp32 -> bf16 hi/lo, fragment-major tiled layout ----------
// chunk c = (((b*16 + r)*16 + kt)*8 + g)*64 + lane
//   row = r*128 + g*16 + (lane&15),  k = kt*32 + (lane>>4)*8 .. +7
__global__ __launch_bounds__(256) void convert_tile_kernel(
    const float* __restrict__ key,
    unsigned short* __restrict__ khi,
    unsigned short* __restrict__ klo)
{
    const size_t c = (size_t)blockIdx.x * 256 + threadIdx.x;
    const int lane = (int)(c & 63);
    const int g    = (int)((c >> 6) & 7);
    const int kt   = (int)((c >> 9) & 15);
    const int r    = (int)((c >> 13) & 15);
    const int b    = (int)(c >> 17);
    const int row  = r * 128 + g * 16 + (lane & 15);
    const int k    = kt * 32 + (lane >> 4) * 8;

    const float4* src = (const float4*)(key + ((size_t)b * LL + row) * DD + k);
    const float4 v0 = src[0], v1 = src[1];
    const float vv[8] = {v0.x, v0.y, v0.z, v0.w, v1.x, v1.y, v1.z, v1.w};

    unsigned short h[8], l[8];
    #pragma unroll
    for (int e = 0; e < 8; ++e) {
        h[e] = bf16_rn(vv[e]);
        l[e] = bf16_rn(vv[e] - bf16_f(h[e]));
    }
    *(bf16x8*)(khi + c * 8) = *(const bf16x8*)h;
    *(bf16x8*)(klo + c * 8) = *(const bf16x8*)l;
}

// ---------- kernel 1: kp[b][i][c] = dot(key[b][i], params[c]) ----------
__global__ __launch_bounds__(256) void kp_kernel(
    const float* __restrict__ key,     // [B*L, D]
    const float* __restrict__ params,  // [C, D]
    float*       __restrict__ kp)      // [B*L, C]
{
    __shared__ float4 pL[CD * (DD / 4)];          // 43 KB
    const int t = threadIdx.x;
    for (int idx = t; idx < CD * (DD / 4); idx += 256)
        pL[idx] = ((const float4*)params)[idx];
    __syncthreads();

    const int ri = blockIdx.x * 256 + t;
    const float4* k4 = (const float4*)key + (size_t)ri * (DD / 4);

    float acc[CD];
    #pragma unroll
    for (int c = 0; c < CD; ++c) acc[c] = 0.f;

    for (int d = 0; d < DD / 4; ++d) {
        const float4 kv = k4[d];
        #pragma unroll
        for (int c = 0; c < CD; ++c) {
            const float4 pv = pL[c * (DD / 4) + d];
            acc[c] += kv.x * pv.x + kv.y * pv.y + kv.z * pv.z + kv.w * pv.w;
        }
    }
    #pragma unroll
    for (int c = 0; c < CD; ++c) kp[(size_t)ri * CD + c] = acc[c];
}

// ---------- kernel 2 (fast path): GEMM from pre-tiled bf16 via global_load_lds ----------
__global__ __launch_bounds__(NT) void gemm_mfma_dma_kernel(
    const unsigned short* __restrict__ khi,  // tiled planes
    const unsigned short* __restrict__ klo,
    const int*   __restrict__ mask,          // [B, L]
    const float* __restrict__ kp,            // [B, L, C]
    float*       __restrict__ out)           // [B, L, L]
{
    __shared__ unsigned short tiles[4][4096];   // Ah, Al, Bh, Bl : 8 KB each
    __shared__ float kps[128 * (CD + 1)];       // 11 KB

    const int t  = threadIdx.x;
    const int bz = blockIdx.z;
    const int i0 = blockIdx.y * 128;
    const int j0 = blockIdx.x * 128;

    // stage bias rows (visible after first k-loop barrier; read in epilogue)
    for (int idx = t; idx < 128 * CD; idx += NT) {
        const int i = idx / CD, c = idx % CD;
        kps[i * (CD + 1) + c] = kp[((size_t)bz * LL + i0 + i) * CD + c];
    }

    const int lane = t & 63, wave = t >> 6;
    const int wr = wave >> 1, wc = wave & 1;
    const int quad = lane >> 4, l16 = lane & 15;

    // wave w stages plane-tile w: 0=Ah 1=Al 2=Bh 3=Bl
    const unsigned short* plane = (wave & 1) ? klo : khi;
    const int rblk = (wave < 2) ? blockIdx.y : blockIdx.x;
    const unsigned short* gbase = plane + ((size_t)bz * 16 + rblk) * 16 * 4096;
    unsigned short* lbase = &tiles[wave][0];

    f32x4 acc[4][4];
    #pragma unroll
    for (int mt = 0; mt < 4; ++mt)
        #pragma unroll
        for (int nt = 0; nt < 4; ++nt)
            acc[mt][nt] = (f32x4){0.f, 0.f, 0.f, 0.f};

    for (int kt = 0; kt < DD / 32; ++kt) {
        // ---- DMA stage: 8 KB per wave, lane-ordered chunks ----
        const unsigned short* gt = gbase + (size_t)kt * 4096;
        #pragma unroll
        for (int seg = 0; seg < 8; ++seg)
            dma16(gt + seg * 512 + lane * 8, lbase + seg * 512);
        __syncthreads();

        // ---- fragments: contiguous ds_read_b128, conflict-free ----
        bf16x8 fah[4], fal[4], fbh[4], fbl[4];
        #pragma unroll
        for (int x = 0; x < 4; ++x) {
            const int ga = ((wr * 4 + x) * 64 + lane) * 8;
            const int gb = ((wc * 4 + x) * 64 + lane) * 8;
            fah[x] = *(const bf16x8*)&tiles[0][ga];
            fal[x] = *(const bf16x8*)&tiles[1][ga];
            fbh[x] = *(const bf16x8*)&tiles[2][gb];
            fbl[x] = *(const bf16x8*)&tiles[3][gb];
        }

        // ---- 48 MFMAs: hi*hi + hi*lo + lo*hi ----
        #pragma unroll
        for (int mt = 0; mt < 4; ++mt)
            #pragma unroll
            for (int nt = 0; nt < 4; ++nt) {
                acc[mt][nt] = __builtin_amdgcn_mfma_f32_16x16x32_bf16(fah[mt], fbh[nt], acc[mt][nt], 0, 0, 0);
                acc[mt][nt] = __builtin_amdgcn_mfma_f32_16x16x32_bf16(fah[mt], fbl[nt], acc[mt][nt], 0, 0, 0);
                acc[mt][nt] = __builtin_amdgcn_mfma_f32_16x16x32_bf16(fal[mt], fbh[nt], acc[mt][nt], 0, 0, 0);
            }
        __syncthreads();
    }

    // ---- epilogue: bias + mask + store ----
    const int* maskb = mask + (size_t)bz * LL;
    int mkv[4];
    #pragma unroll
    for (int nt = 0; nt < 4; ++nt)
        mkv[nt] = maskb[j0 + wc * 64 + nt * 16 + l16];

    #pragma unroll
    for (int mt = 0; mt < 4; ++mt)
        #pragma unroll
        for (int r = 0; r < 4; ++r) {
            const int li   = wr * 64 + mt * 16 + quad * 4 + r;
            const int grow = i0 + li;
            float* orow = out + ((size_t)bz * LL + grow) * LL;
            #pragma unroll
            for (int nt = 0; nt < 4; ++nt) {
                const int col = j0 + wc * 64 + nt * 16 + l16;
                int rel = col - grow;
                rel = rel < -CLIPD ? -CLIPD : (rel > CLIPD ? CLIPD : rel);
                const float v = acc[mt][nt][r] + kps[li * (CD + 1) + rel + CLIPD];
                orow[col] = mkv[nt] ? -1e20f : v;
            }
        }
}

// ---------- kernel 2 (fallback, R3): in-kernel conversion GEMM ----------
__global__ __launch_bounds__(NT) void gemm_mfma_kernel(
    const float* __restrict__ key,
    const int*   __restrict__ mask,
    const float* __restrict__ kp,
    float*       __restrict__ out)
{
    __shared__ unsigned short Ah[128 * KPAD];
    __shared__ unsigned short Al[128 * KPAD];
    __shared__ unsigned short Bhs[128 * KPAD];
    __shared__ unsigned short Bls[128 * KPAD];
    __shared__ float kps[128 * (CD + 1)];

    const int t  = threadIdx.x;
    const int bz = blockIdx.z;
    const int i0 = blockIdx.y * 128;
    const int j0 = blockIdx.x * 128;

    const float4* keyb4 = (const float4*)(key + (size_t)bz * LL * DD);

    for (int idx = t; idx < 128 * CD; idx += NT) {
        const int i = idx / CD, c = idx % CD;
        kps[i * (CD + 1) + c] = kp[((size_t)bz * LL + i0 + i) * CD + c];
    }

    const int lane = t & 63, wave = t >> 6;
    const int wr = wave >> 1, wc = wave & 1;
    const int quad = lane >> 4, l16 = lane & 15;

    f32x4 acc[4][4];
    #pragma unroll
    for (int mt = 0; mt < 4; ++mt)
        #pragma unroll
        for (int nt = 0; nt < 4; ++nt)
            acc[mt][nt] = (f32x4){0.f, 0.f, 0.f, 0.f};

    for (int kt = 0; kt < DD / 32; ++kt) {
        #pragma unroll
        for (int r = 0; r < 2; ++r) {
            const int flat = t + NT * r;
            const int row  = flat >> 2;
            const int kq2  = flat & 3;
            #pragma unroll
            for (int h = 0; h < 2; ++h) {
                const int kq = kq2 * 2 + h;
                const float4 av = keyb4[(size_t)(i0 + row) * (DD / 4) + kt * 8 + kq];
                const float4 bv = keyb4[(size_t)(j0 + row) * (DD / 4) + kt * 8 + kq];
                ushort4 ah4, al4, bh4, bl4;
                ah4.x = bf16_rn(av.x); al4.x = bf16_rn(av.x - bf16_f(ah4.x));
                ah4.y = bf16_rn(av.y); al4.y = bf16_rn(av.y - bf16_f(ah4.y));
                ah4.z = bf16_rn(av.z); al4.z = bf16_rn(av.z - bf16_f(ah4.z));
                ah4.w = bf16_rn(av.w); al4.w = bf16_rn(av.w - bf16_f(ah4.w));
                bh4.x = bf16_rn(bv.x); bl4.x = bf16_rn(bv.x - bf16_f(bh4.x));
                bh4.y = bf16_rn(bv.y); bl4.y = bf16_rn(bv.y - bf16_f(bh4.y));
                bh4.z = bf16_rn(bv.z); bl4.z = bf16_rn(bv.z - bf16_f(bh4.z));
                bh4.w = bf16_rn(bv.w); bl4.w = bf16_rn(bv.w - bf16_f(bh4.w));
                *(ushort4*)&Ah [row * KPAD + kq * 4] = ah4;
                *(ushort4*)&Al [row * KPAD + kq * 4] = al4;
                *(ushort4*)&Bhs[row * KPAD + kq * 4] = bh4;
                *(ushort4*)&Bls[row * KPAD + kq * 4] = bl4;
            }
        }
        __syncthreads();

        bf16x8 fah[4], fal[4], fbh[4], fbl[4];
        #pragma unroll
        for (int x = 0; x < 4; ++x) {
            const int m = wr * 64 + x * 16 + l16;
            const int n = wc * 64 + x * 16 + l16;
            fah[x] = *(const bf16x8*)&Ah [m * KPAD + quad * 8];
            fal[x] = *(const bf16x8*)&Al [m * KPAD + quad * 8];
            fbh[x] = *(const bf16x8*)&Bhs[n * KPAD + quad * 8];
            fbl[x] = *(const bf16x8*)&Bls[n * KPAD + quad * 8];
        }

        #pragma unroll
        for (int mt = 0; mt < 4; ++mt)
            #pragma unroll
            for (int nt = 0; nt < 4; ++nt) {
                acc[mt][nt] = __builtin_amdgcn_mfma_f32_16x16x32_bf16(fah[mt], fbh[nt], acc[mt][nt], 0, 0, 0);
                acc[mt][nt] = __builtin_amdgcn_mfma_f32_16x16x32_bf16(fah[mt], fbl[nt], acc[mt][nt], 0, 0, 0);
                acc[mt][nt] = __builtin_amdgcn_mfma_f32_16x16x32_bf16(fal[mt], fbh[nt], acc[mt][nt], 0, 0, 0);
            }
        __syncthreads();
    }

    const int* maskb = mask + (size_t)bz * LL;
    int mkv[4];
    #pragma unroll
    for (int nt = 0; nt < 4; ++nt)
        mkv[nt] = maskb[j0 + wc * 64 + nt * 16 + l16];

    #pragma unroll
    for (int mt = 0; mt < 4; ++mt)
        #pragma unroll
        for (int r = 0; r < 4; ++r) {
            const int li   = wr * 64 + mt * 16 + quad * 4 + r;
            const int grow = i0 + li;
            float* orow = out + ((size_t)bz * LL + grow) * LL;
            #pragma unroll
            for (int nt = 0; nt < 4; ++nt) {
                const int col = j0 + wc * 64 + nt * 16 + l16;
                int rel = col - grow;
                rel = rel < -CLIPD ? -CLIPD : (rel > CLIPD ? CLIPD : rel);
                const float v = acc[mt][nt][r] + kps[li * (CD + 1) + rel + CLIPD];
                orow[col] = mkv[nt] ? -1e20f : v;
            }
        }
}

// ---------- kernel 3: in-place row softmax ----------
__global__ __launch_bounds__(256) void softmax_kernel(float* __restrict__ out) {
    const int row  = blockIdx.x * 4 + (threadIdx.x >> 6);
    const int lane = threadIdx.x & 63;
    float4* r4 = (float4*)out + (size_t)row * (LL / 4);

    float4 v[8];
    float mx = -INFINITY;
    #pragma unroll
    for (int c = 0; c < 8; ++c) {
        v[c] = r4[lane + 64 * c];
        mx = fmaxf(mx, fmaxf(fmaxf(v[c].x, v[c].y), fmaxf(v[c].z, v[c].w)));
    }
    #pragma unroll
    for (int off = 32; off; off >>= 1) mx = fmaxf(mx, __shfl_xor(mx, off));

    float s = 0.f;
    #pragma unroll
    for (int c = 0; c < 8; ++c) {
        v[c].x = __expf(v[c].x - mx); v[c].y = __expf(v[c].y - mx);
        v[c].z = __expf(v[c].z - mx); v[c].w = __expf(v[c].w - mx);
        s += v[c].x + v[c].y + v[c].z + v[c].w;
    }
    #pragma unroll
    for (int off = 32; off; off >>= 1) s += __shfl_xor(s, off);

    const float inv = 1.0f / s;
    #pragma unroll
    for (int c = 0; c < 8; ++c) {
        v[c].x *= inv; v[c].y *= inv; v[c].z *= inv; v[c].w *= inv;
        r4[lane + 64 * c] = v[c];
    }
}

extern "C" void kernel_launch(void* const* d_in, const int* in_sizes, int n_in,
                              void* d_out, int out_size, void* d_ws, size_t ws_size,
                              hipStream_t stream) {
    const float* key    = (const float*)d_in[0];
    const int*   mask   = (const int*)d_in[1];
    const float* params = (const float*)d_in[2];
    float*       out    = (float*)d_out;

    const int B = in_sizes[0] / (LL * DD);        // 16
    const int nrows = B * LL;                     // 32768

    const size_t kp_bytes    = (size_t)nrows * CD * sizeof(float);      // 2.75 MB
    const size_t plane_elems = (size_t)B * LL * DD;                     // 16.8M
    const size_t need        = kp_bytes + 2 * plane_elems * 2;          // ~70 MB

    float* kp = (float*)d_ws;
    kp_kernel<<<dim3(nrows / 256), dim3(256), 0, stream>>>(key, params, kp);

    dim3 ggrid(LL / 128, LL / 128, B);            // 16 x 16 x 16

    if (ws_size >= need) {
        unsigned short* khi = (unsigned short*)((char*)d_ws + kp_bytes);
        unsigned short* klo = khi + plane_elems;
        convert_tile_kernel<<<dim3((unsigned)(plane_elems / 8 / 256)), dim3(256), 0, stream>>>(key, khi, klo);
        gemm_mfma_dma_kernel<<<ggrid, dim3(NT), 0, stream>>>(khi, klo, mask, kp, out);
    } else {
        gemm_mfma_kernel<<<ggrid, dim3(NT), 0, stream>>>(key, mask, kp, out);
    }

    softmax_kernel<<<dim3(nrows / 4), dim3(256), 0, stream>>>(out);
}